// Round 5
// baseline (603.928 us; speedup 1.0000x reference)
//
#include <hip/hip_runtime.h>
#include <hip/hip_bf16.h>
#include <math.h>

#define S_LEN 4096
#define DMODEL 768
#define NHEAD 12
#define HDIM 64
#define DFF_ 3072
#define MROWS 8192  // B*S

typedef __bf16 bf16;
typedef __bf16 bf16x4 __attribute__((ext_vector_type(4)));
typedef __bf16 bf16x8 __attribute__((ext_vector_type(8)));
typedef float f32x4 __attribute__((ext_vector_type(4)));

union F4 { float4 v; float f[4]; };
union U2 { bf16 h[2]; unsigned u; };
union U8 { unsigned u[4]; bf16x8 v; };

__device__ __forceinline__ void gld_lds16(void* lds, const void* g) {
    __builtin_amdgcn_global_load_lds(
        (const __attribute__((address_space(1))) unsigned int*)g,
        (__attribute__((address_space(3))) unsigned int*)lds, 16, 0, 0);
}

// ---------------- LayerNorm ----------------
template<typename OUT>
__global__ __launch_bounds__(256) void ln_kernel(const float* __restrict__ x,
                                                 const float* __restrict__ g,
                                                 const float* __restrict__ bta,
                                                 OUT* __restrict__ out) {
    const int row = blockIdx.x;
    const int t = threadIdx.x;
    const float* xr = x + (size_t)row * DMODEL;
    float v0 = xr[t], v1 = xr[t + 256], v2 = xr[t + 512];
    float s = v0 + v1 + v2;
    float ss = v0 * v0 + v1 * v1 + v2 * v2;
    for (int o = 32; o > 0; o >>= 1) {
        s += __shfl_down(s, o, 64);
        ss += __shfl_down(ss, o, 64);
    }
    __shared__ float sm[4], sm2[4];
    const int w = t >> 6, lane = t & 63;
    if (lane == 0) { sm[w] = s; sm2[w] = ss; }
    __syncthreads();
    s = sm[0] + sm[1] + sm[2] + sm[3];
    ss = sm2[0] + sm2[1] + sm2[2] + sm2[3];
    const float mu = s * (1.0f / DMODEL);
    const float var = ss * (1.0f / DMODEL) - mu * mu;
    const float rs = rsqrtf(var + 1e-5f);
    OUT* orow = out + (size_t)row * DMODEL;
    orow[t]       = (OUT)((v0 - mu) * rs * g[t]       + bta[t]);
    orow[t + 256] = (OUT)((v1 - mu) * rs * g[t + 256] + bta[t + 256]);
    orow[t + 512] = (OUT)((v2 - mu) * rs * g[t + 512] + bta[t + 512]);
}

// ---------------- weight transpose+convert: fp32 [K][N] -> bf16 [N][K] ----------------
__global__ __launch_bounds__(256) void wtrans_kernel(const float* __restrict__ W,
                                                     bf16* __restrict__ Wt,
                                                     int K, int N) {
    __shared__ float tile[64][65];
    const int tid = threadIdx.x;
    const int n0 = blockIdx.x * 64, k0 = blockIdx.y * 64;
    const int lr = tid >> 4, lc = (tid & 15) << 2;
#pragma unroll
    for (int i = 0; i < 4; ++i) {
        const int r = lr + i * 16;
        F4 w; w.v = *(const float4*)&W[(size_t)(k0 + r) * N + n0 + lc];
#pragma unroll
        for (int j = 0; j < 4; ++j) tile[r][lc + j] = w.f[j];
    }
    __syncthreads();
#pragma unroll
    for (int i = 0; i < 4; ++i) {
        const int n = lr + i * 16;
        bf16x4 o;
#pragma unroll
        for (int j = 0; j < 4; ++j) o[j] = (bf16)tile[lc + j][n];
        *(bf16x4*)&Wt[(size_t)(n0 + n) * K + k0 + lc] = o;
    }
}

// ---------------- bf16 MFMA GEMM (m97 structure), MT x 128 tile ----------------
// MT=128: 4 waves each 64x64.  MT=64: 4 waves each 64x32 (higher grid occupancy
// for small-N GEMMs: 384 blocks -> 768 = 3/CU uniform).
template<int MT, bool RELU, bool RES, bool OUT_BF16>
__global__ __launch_bounds__(256) void mgemm_kernel(
    const bf16* __restrict__ A,
    const bf16* __restrict__ Wt0, const float* __restrict__ bias0, void* __restrict__ C0,
    const bf16* __restrict__ Wt1, const float* __restrict__ bias1, void* __restrict__ C1,
    const bf16* __restrict__ Wt2, const float* __restrict__ bias2, void* __restrict__ C2,
    const float* __restrict__ R, int M, int N, int K,
    float sc0, float sc1, float sc2) {
    const bf16* Wt = Wt0; const float* bias = bias0; void* C = C0; float sc = sc0;
    if (blockIdx.z == 1) { Wt = Wt1; bias = bias1; C = C1; sc = sc1; }
    if (blockIdx.z == 2) { Wt = Wt2; bias = bias2; C = C2; sc = sc2; }

    constexpr int NI = (MT == 128) ? 4 : 2;   // 16-col frags per wave
    __shared__ bf16 As[MT * 32];
    __shared__ bf16 Bs[128 * 32];

    const int tid = threadIdx.x;
    const int wave = tid >> 6, lane = tid & 63;
    const int row0 = blockIdx.y * MT, col0 = blockIdx.x * 128;
    const int wr = (MT == 128) ? (wave >> 1) * 64 : 0;
    const int wc = (MT == 128) ? (wave & 1) * 64 : wave * 32;
    const int mrow = lane & 15, kq = (lane >> 4) * 8;

    const int st_row = (lane >> 2);
    const int st_off = (lane & 3) * 16;

    f32x4 acc[4][NI] = {};

    const char* Ab = (const char*)(A + (size_t)row0 * K);
    const char* Bb = (const char*)(Wt + (size_t)col0 * K);
    const size_t strideA = (size_t)K * 2;

    for (int k0 = 0; k0 < K; k0 += 32) {
        if (MT == 128) {
#pragma unroll
            for (int issue = 0; issue < 2; ++issue) {
                const int r = wave * 32 + issue * 16 + st_row;
                gld_lds16((char*)As + (wave * 32 + issue * 16) * 64,
                          Ab + (size_t)r * strideA + k0 * 2 + st_off);
            }
        } else {
            const int r = wave * 16 + st_row;
            gld_lds16((char*)As + (wave * 16) * 64,
                      Ab + (size_t)r * strideA + k0 * 2 + st_off);
        }
#pragma unroll
        for (int issue = 0; issue < 2; ++issue) {
            const int r = wave * 32 + issue * 16 + st_row;
            gld_lds16((char*)Bs + (wave * 32 + issue * 16) * 64,
                      Bb + (size_t)r * strideA + k0 * 2 + st_off);
        }
        __syncthreads();
        bf16x8 af[4], bfr[NI];
#pragma unroll
        for (int mi = 0; mi < 4; ++mi)
            af[mi] = *(const bf16x8*)&As[(wr + mi * 16 + mrow) * 32 + kq];
#pragma unroll
        for (int ni = 0; ni < NI; ++ni)
            bfr[ni] = *(const bf16x8*)&Bs[(wc + ni * 16 + mrow) * 32 + kq];
#pragma unroll
        for (int mi = 0; mi < 4; ++mi)
#pragma unroll
            for (int ni = 0; ni < NI; ++ni)
                acc[mi][ni] = __builtin_amdgcn_mfma_f32_16x16x32_bf16(
                    af[mi], bfr[ni], acc[mi][ni], 0, 0, 0);
        __syncthreads();
    }

    const int quad = lane >> 4;
    float bv[NI];
#pragma unroll
    for (int ni = 0; ni < NI; ++ni) bv[ni] = bias[col0 + wc + ni * 16 + mrow];
#pragma unroll
    for (int mi = 0; mi < 4; ++mi) {
#pragma unroll
        for (int r = 0; r < 4; ++r) {
            const int row = row0 + wr + mi * 16 + quad * 4 + r;
#pragma unroll
            for (int ni = 0; ni < NI; ++ni) {
                const int col = col0 + wc + ni * 16 + mrow;
                float v = acc[mi][ni][r] + bv[ni];
                if (RES) v += R[(size_t)row * N + col];
                v *= sc;
                if (RELU) v = fmaxf(v, 0.0f);
                if (OUT_BF16) ((bf16*)C)[(size_t)row * N + col] = (bf16)v;
                else          ((float*)C)[(size_t)row * N + col] = v;
            }
        }
    }
}

// ---------------- Transposed-S MFMA flash attention ----------------
// S^T = K·Q^T so each lane's C-column is a fixed query (q = lane&15).
// P^T re-layout for O^T = V^T·P^T via quad-level shfl — no LDS round trip.
// Q pre-scaled by 0.125*log2(e) in the QKV epilogue.
// grid: (64, H, B) = 1536 blocks (6/CU); heavy q-tiles dispatched first.
__global__ __launch_bounds__(256) void mattn_kernel(
    const bf16* __restrict__ Q, const bf16* __restrict__ K,
    const bf16* __restrict__ V, const int* __restrict__ amask,
    bf16* __restrict__ O) {
    const int qt = 63 - blockIdx.x;  // heavy tiles first
    const int h = blockIdx.y, b = blockIdx.z;

    __shared__ bf16 Ks[64][68];   // [key][d]  (136 B rows: measured conflict-free)
    __shared__ bf16 Vt[64][68];   // [d][key]
    __shared__ bf16 Os[64][68];   // epilogue bounce
    __shared__ float mk[64];
    __shared__ int flagv;

    const int tid = threadIdx.x;
    const int wave = tid >> 6, lane = tid & 63;
    const int l = lane & 15, quad = lane >> 4;
    const int qh = quad >> 1;
    const int srcA = (quad & 1) * 32 + l;
    const int srcB = srcA + 16;
    const float NEG_INF = -__builtin_huge_valf();

    const int kr = tid >> 2, ks = (tid & 3) * 16;          // K tile staging
    const int vk0 = (tid & 31) * 2, vds = (tid >> 5) * 8;  // V transpose staging

    // Q fragments (B-operand), pre-scaled, held in registers
    const bf16* Qb = Q + (size_t)(b * S_LEN + qt * 64 + wave * 16 + l) * DMODEL + h * HDIM;
    const bf16x8 qf0 = *(const bf16x8*)(Qb + quad * 8);
    const bf16x8 qf1 = *(const bf16x8*)(Qb + 32 + quad * 8);

    float m_run = NEG_INF, l_run = 0.0f;
    f32x4 acc[4] = {};

    for (int kt = 0; kt <= qt; ++kt) {
        __syncthreads();  // prior iter's LDS reads complete
        {   // stage K [key][d]
            const bf16* kg = K + (size_t)(b * S_LEN + kt * 64 + kr) * DMODEL + h * HDIM + ks;
            *(bf16x8*)&Ks[kr][ks]     = *(const bf16x8*)kg;
            *(bf16x8*)&Ks[kr][ks + 8] = *(const bf16x8*)(kg + 8);
        }
        {   // stage V transposed [d][key], packed pair writes
            const bf16* vg = V + (size_t)(b * S_LEN + kt * 64 + vk0) * DMODEL + h * HDIM + vds;
            bf16x8 v0 = *(const bf16x8*)vg;
            bf16x8 v1 = *(const bf16x8*)(vg + DMODEL);
#pragma unroll
            for (int i = 0; i < 8; ++i) {
                U2 w; w.h[0] = v0[i]; w.h[1] = v1[i];
                *(unsigned*)&Vt[vds + i][vk0] = w.u;
            }
        }
        if (wave == 0) {
            const int mv = amask[b * S_LEN + kt * 64 + lane];
            mk[lane] = mv ? 0.0f : NEG_INF;
            unsigned long long bal = __ballot(mv != 0);
            if (lane == 0) flagv = (bal == ~0ULL);
        }
        __syncthreads();
        const int allv = flagv;

        // S^T = K · Q^T : lane holds S^T[key = mi*16+quad*4+r][q = l]
        f32x4 sreg[4] = {};
#pragma unroll
        for (int mi = 0; mi < 4; ++mi) {
            bf16x8 kf0 = *(const bf16x8*)&Ks[mi * 16 + l][quad * 8];
            bf16x8 kf1 = *(const bf16x8*)&Ks[mi * 16 + l][32 + quad * 8];
            sreg[mi] = __builtin_amdgcn_mfma_f32_16x16x32_bf16(kf0, qf0, sreg[mi], 0, 0, 0);
            sreg[mi] = __builtin_amdgcn_mfma_f32_16x16x32_bf16(kf1, qf1, sreg[mi], 0, 0, 0);
        }
        if (!allv) {
#pragma unroll
            for (int mi = 0; mi < 4; ++mi) {
                F4 m4; m4.v = *(const float4*)&mk[mi * 16 + quad * 4];
#pragma unroll
                for (int r = 0; r < 4; ++r) sreg[mi][r] += m4.f[r];
            }
        }
        if (kt == qt) {   // diagonal tile: causal mask
#pragma unroll
            for (int mi = 0; mi < 4; ++mi)
#pragma unroll
                for (int r = 0; r < 4; ++r)
                    if (mi * 16 + quad * 4 + r > wave * 16 + l)
                        sreg[mi][r] = NEG_INF;
        }

        // online softmax (per-lane: one query's 16 keys; 2 shfl levels for 64)
        float mloc = sreg[0][0];
#pragma unroll
        for (int mi = 0; mi < 4; ++mi)
#pragma unroll
            for (int r = 0; r < 4; ++r) mloc = fmaxf(mloc, sreg[mi][r]);
        mloc = fmaxf(mloc, __shfl_xor(mloc, 16, 64));
        mloc = fmaxf(mloc, __shfl_xor(mloc, 32, 64));
        const float mn = fmaxf(m_run, mloc);
        const float alpha = __builtin_amdgcn_exp2f(m_run - mn);
        m_run = mn;
        float ls = 0.0f;
#pragma unroll
        for (int mi = 0; mi < 4; ++mi)
#pragma unroll
            for (int r = 0; r < 4; ++r) {
                const float p = __builtin_amdgcn_exp2f(sreg[mi][r] - mn);
                sreg[mi][r] = p;
                ls += p;
            }
        ls += __shfl_xor(ls, 16, 64);
        ls += __shfl_xor(ls, 32, 64);
        l_run = l_run * alpha + ls;
#pragma unroll
        for (int mi = 0; mi < 4; ++mi)
#pragma unroll
            for (int r = 0; r < 4; ++r) acc[mi][r] *= alpha;

        // pack P^T to bf16 dwords
        unsigned pk[4][2];
#pragma unroll
        for (int mi = 0; mi < 4; ++mi) {
            U2 w0; w0.h[0] = (bf16)sreg[mi][0]; w0.h[1] = (bf16)sreg[mi][1];
            U2 w1; w1.h[0] = (bf16)sreg[mi][2]; w1.h[1] = (bf16)sreg[mi][3];
            pk[mi][0] = w0.u; pk[mi][1] = w1.u;
        }
        // assemble B-frags of P^T via quad-level shfl
        bf16x8 pfrag[2];
#pragma unroll
        for (int kc = 0; kc < 2; ++kc) {
            U8 u;
#pragma unroll
            for (int t = 0; t < 2; ++t) {
                const unsigned a0 = (unsigned)__shfl((int)pk[2 * kc][t],     srcA, 64);
                const unsigned b0 = (unsigned)__shfl((int)pk[2 * kc + 1][t], srcA, 64);
                u.u[t] = qh ? b0 : a0;
                const unsigned a1 = (unsigned)__shfl((int)pk[2 * kc][t],     srcB, 64);
                const unsigned b1 = (unsigned)__shfl((int)pk[2 * kc + 1][t], srcB, 64);
                u.u[2 + t] = qh ? b1 : a1;
            }
            pfrag[kc] = u.v;
        }
        // O^T += V^T · P^T
#pragma unroll
        for (int mi = 0; mi < 4; ++mi) {
            bf16x8 vf0 = *(const bf16x8*)&Vt[mi * 16 + l][quad * 8];
            bf16x8 vf1 = *(const bf16x8*)&Vt[mi * 16 + l][32 + quad * 8];
            acc[mi] = __builtin_amdgcn_mfma_f32_16x16x32_bf16(vf0, pfrag[0], acc[mi], 0, 0, 0);
            acc[mi] = __builtin_amdgcn_mfma_f32_16x16x32_bf16(vf1, pfrag[1], acc[mi], 0, 0, 0);
        }
    }

    // epilogue: lane owns query q = wave*16+l, d = mi*16+quad*4+r
    const float rinv = 1.0f / l_run;
#pragma unroll
    for (int mi = 0; mi < 4; ++mi) {
        U2 w0; w0.h[0] = (bf16)(acc[mi][0] * rinv); w0.h[1] = (bf16)(acc[mi][1] * rinv);
        U2 w1; w1.h[0] = (bf16)(acc[mi][2] * rinv); w1.h[1] = (bf16)(acc[mi][3] * rinv);
        *(unsigned*)&Os[wave * 16 + l][mi * 16 + quad * 4]     = w0.u;
        *(unsigned*)&Os[wave * 16 + l][mi * 16 + quad * 4 + 2] = w1.u;
    }
    __syncthreads();
    {   // coalesced store
        const int orow = tid >> 2, oseg = (tid & 3) * 16;
        bf16* Og = O + (size_t)(b * S_LEN + qt * 64 + orow) * DMODEL + h * HDIM + oseg;
        *(bf16x8*)Og       = *(const bf16x8*)&Os[orow][oseg];
        *(bf16x8*)(Og + 8) = *(const bf16x8*)&Os[orow][oseg + 8];
    }
}

// ---------------- launcher ----------------
extern "C" void kernel_launch(void* const* d_in, const int* in_sizes, int n_in,
                              void* d_out, int out_size, void* d_ws, size_t ws_size,
                              hipStream_t stream) {
    const float* x     = (const float*)d_in[0];
    const int*   amask = (const int*)  d_in[1];
    const float* ln1_g = (const float*)d_in[2];
    const float* ln1_b = (const float*)d_in[3];
    const float* ln2_g = (const float*)d_in[4];
    const float* ln2_b = (const float*)d_in[5];
    const float* Wq = (const float*)d_in[6];  const float* bq = (const float*)d_in[7];
    const float* Wk = (const float*)d_in[8];  const float* bk = (const float*)d_in[9];
    const float* Wv = (const float*)d_in[10]; const float* bv = (const float*)d_in[11];
    const float* Wo = (const float*)d_in[12]; const float* bo = (const float*)d_in[13];
    const float* W1 = (const float*)d_in[14]; const float* b1 = (const float*)d_in[15];
    const float* W2 = (const float*)d_in[16]; const float* b2 = (const float*)d_in[17];
    float* out = (float*)d_out;

    char* ws = (char*)d_ws;
    const size_t WSML = (size_t)DMODEL * DMODEL * 2;
    const size_t WBIG = (size_t)DMODEL * DFF_ * 2;
    bf16* Wqt = (bf16*)(ws + 0 * WSML);
    bf16* Wkt = (bf16*)(ws + 1 * WSML);
    bf16* Wvt = (bf16*)(ws + 2 * WSML);
    bf16* Wot = (bf16*)(ws + 3 * WSML);
    bf16* W1t = (bf16*)(ws + 4 * WSML);
    bf16* W2t = (bf16*)(ws + 4 * WSML + WBIG);
    char* act = ws + 4 * WSML + 2 * WBIG;

    const size_t HB = (size_t)MROWS * DMODEL * 2;   // bf16 activation
    const size_t FB = (size_t)MROWS * DMODEL * 4;   // fp32 activation
    bf16*  h    = (bf16*)(act);            // LN1 out; later ctx; later h2
    bf16*  qb   = (bf16*)(act + HB);
    bf16*  kb   = (bf16*)(act + 2 * HB);
    bf16*  vb   = (bf16*)(act + 3 * HB);
    bf16*  ctx  = h;
    float* x1   = (float*)(act + 4 * HB);
    bf16*  f    = (bf16*)(act + 4 * HB + FB);
    bf16*  h2   = h;

    const float SCL = 0.125f * 1.44269504089f;  // 1/sqrt(64) * log2(e), folded into Q

    // 0. weight transpose+convert
    wtrans_kernel<<<dim3(DMODEL / 64, DMODEL / 64), 256, 0, stream>>>(Wq, Wqt, DMODEL, DMODEL);
    wtrans_kernel<<<dim3(DMODEL / 64, DMODEL / 64), 256, 0, stream>>>(Wk, Wkt, DMODEL, DMODEL);
    wtrans_kernel<<<dim3(DMODEL / 64, DMODEL / 64), 256, 0, stream>>>(Wv, Wvt, DMODEL, DMODEL);
    wtrans_kernel<<<dim3(DMODEL / 64, DMODEL / 64), 256, 0, stream>>>(Wo, Wot, DMODEL, DMODEL);
    wtrans_kernel<<<dim3(DFF_ / 64, DMODEL / 64), 256, 0, stream>>>(W1, W1t, DMODEL, DFF_);
    wtrans_kernel<<<dim3(DMODEL / 64, DFF_ / 64), 256, 0, stream>>>(W2, W2t, DFF_, DMODEL);

    // 1. LN1 -> h (bf16)
    ln_kernel<bf16><<<MROWS, 256, 0, stream>>>(x, ln1_g, ln1_b, h);
    // 2. QKV fused, bf16 out; Q pre-scaled by SCL  (1152 blocks)
    mgemm_kernel<128, false, false, true><<<dim3(DMODEL / 128, MROWS / 128, 3), 256, 0, stream>>>(
        h, Wqt, bq, qb, Wkt, bk, kb, Wvt, bv, vb, nullptr, MROWS, DMODEL, DMODEL,
        SCL, 1.0f, 1.0f);
    // 3. transposed-S MFMA flash attention -> ctx (bf16)  (1536 blocks)
    mattn_kernel<<<dim3(64, NHEAD, 2), 256, 0, stream>>>(qb, kb, vb, amask, ctx);
    // 4. out proj + residual(x) -> x1 (fp32)  (MT=64: 768 blocks)
    mgemm_kernel<64, false, true, false><<<dim3(DMODEL / 128, MROWS / 64, 1), 256, 0, stream>>>(
        ctx, Wot, bo, x1, Wot, bo, x1, Wot, bo, x1, x, MROWS, DMODEL, DMODEL,
        1.0f, 1.0f, 1.0f);
    // 5. LN2 -> h2 (bf16)
    ln_kernel<bf16><<<MROWS, 256, 0, stream>>>(x1, ln2_g, ln2_b, h2);
    // 6. FF1 + relu -> f (bf16)  (1536 blocks)
    mgemm_kernel<128, true, false, true><<<dim3(DFF_ / 128, MROWS / 128, 1), 256, 0, stream>>>(
        h2, W1t, b1, f, W1t, b1, f, W1t, b1, f, nullptr, MROWS, DFF_, DMODEL,
        1.0f, 1.0f, 1.0f);
    // 7. FF2 + residual(x1) -> out (fp32)  (MT=64: 768 blocks)
    mgemm_kernel<64, false, true, false><<<dim3(DMODEL / 128, MROWS / 64, 1), 256, 0, stream>>>(
        f, W2t, b2, out, W2t, b2, out, W2t, b2, out, x1, MROWS, DMODEL, DFF_,
        1.0f, 1.0f, 1.0f);
}

// Round 6
// 504.815 us; speedup vs baseline: 1.1963x; 1.1963x over previous
//
#include <hip/hip_runtime.h>
#include <hip/hip_bf16.h>
#include <math.h>

#define S_LEN 4096
#define DMODEL 768
#define NHEAD 12
#define HDIM 64
#define DFF_ 3072
#define MROWS 8192  // B*S

typedef __bf16 bf16;
typedef __bf16 bf16x4 __attribute__((ext_vector_type(4)));
typedef __bf16 bf16x8 __attribute__((ext_vector_type(8)));
typedef float f32x4 __attribute__((ext_vector_type(4)));

union F4 { float4 v; float f[4]; };
union U2 { bf16 h[2]; unsigned u; };
union U8 { unsigned u[4]; bf16x8 v; };

__device__ __forceinline__ void gld_lds16(void* lds, const void* g) {
    __builtin_amdgcn_global_load_lds(
        (const __attribute__((address_space(1))) unsigned int*)g,
        (__attribute__((address_space(3))) unsigned int*)lds, 16, 0, 0);
}

// ---------------- LayerNorm ----------------
template<typename OUT>
__global__ __launch_bounds__(256) void ln_kernel(const float* __restrict__ x,
                                                 const float* __restrict__ g,
                                                 const float* __restrict__ bta,
                                                 OUT* __restrict__ out) {
    const int row = blockIdx.x;
    const int t = threadIdx.x;
    const float* xr = x + (size_t)row * DMODEL;
    float v0 = xr[t], v1 = xr[t + 256], v2 = xr[t + 512];
    float s = v0 + v1 + v2;
    float ss = v0 * v0 + v1 * v1 + v2 * v2;
    for (int o = 32; o > 0; o >>= 1) {
        s += __shfl_down(s, o, 64);
        ss += __shfl_down(ss, o, 64);
    }
    __shared__ float sm[4], sm2[4];
    const int w = t >> 6, lane = t & 63;
    if (lane == 0) { sm[w] = s; sm2[w] = ss; }
    __syncthreads();
    s = sm[0] + sm[1] + sm[2] + sm[3];
    ss = sm2[0] + sm2[1] + sm2[2] + sm2[3];
    const float mu = s * (1.0f / DMODEL);
    const float var = ss * (1.0f / DMODEL) - mu * mu;
    const float rs = rsqrtf(var + 1e-5f);
    OUT* orow = out + (size_t)row * DMODEL;
    orow[t]       = (OUT)((v0 - mu) * rs * g[t]       + bta[t]);
    orow[t + 256] = (OUT)((v1 - mu) * rs * g[t + 256] + bta[t + 256]);
    orow[t + 512] = (OUT)((v2 - mu) * rs * g[t + 512] + bta[t + 512]);
}

// ---------------- weight transpose+convert: fp32 [K][N] -> bf16 [N][K] ----------------
__global__ __launch_bounds__(256) void wtrans_kernel(const float* __restrict__ W,
                                                     bf16* __restrict__ Wt,
                                                     int K, int N) {
    __shared__ float tile[64][65];
    const int tid = threadIdx.x;
    const int n0 = blockIdx.x * 64, k0 = blockIdx.y * 64;
    const int lr = tid >> 4, lc = (tid & 15) << 2;
#pragma unroll
    for (int i = 0; i < 4; ++i) {
        const int r = lr + i * 16;
        F4 w; w.v = *(const float4*)&W[(size_t)(k0 + r) * N + n0 + lc];
#pragma unroll
        for (int j = 0; j < 4; ++j) tile[r][lc + j] = w.f[j];
    }
    __syncthreads();
#pragma unroll
    for (int i = 0; i < 4; ++i) {
        const int n = lr + i * 16;
        bf16x4 o;
#pragma unroll
        for (int j = 0; j < 4; ++j) o[j] = (bf16)tile[lc + j][n];
        *(bf16x4*)&Wt[(size_t)(n0 + n) * K + k0 + lc] = o;
    }
}

// ---------------- bf16 MFMA GEMM (m97 structure), MT x 128 tile ----------------
template<int MT, bool RELU, bool RES, bool OUT_BF16>
__global__ __launch_bounds__(256) void mgemm_kernel(
    const bf16* __restrict__ A,
    const bf16* __restrict__ Wt0, const float* __restrict__ bias0, void* __restrict__ C0,
    const bf16* __restrict__ Wt1, const float* __restrict__ bias1, void* __restrict__ C1,
    const bf16* __restrict__ Wt2, const float* __restrict__ bias2, void* __restrict__ C2,
    const float* __restrict__ R, int M, int N, int K,
    float sc0, float sc1, float sc2) {
    const bf16* Wt = Wt0; const float* bias = bias0; void* C = C0; float sc = sc0;
    if (blockIdx.z == 1) { Wt = Wt1; bias = bias1; C = C1; sc = sc1; }
    if (blockIdx.z == 2) { Wt = Wt2; bias = bias2; C = C2; sc = sc2; }

    constexpr int NI = (MT == 128) ? 4 : 2;
    __shared__ bf16 As[MT * 32];
    __shared__ bf16 Bs[128 * 32];

    const int tid = threadIdx.x;
    const int wave = tid >> 6, lane = tid & 63;
    const int row0 = blockIdx.y * MT, col0 = blockIdx.x * 128;
    const int wr = (MT == 128) ? (wave >> 1) * 64 : 0;
    const int wc = (MT == 128) ? (wave & 1) * 64 : wave * 32;
    const int mrow = lane & 15, kq = (lane >> 4) * 8;

    const int st_row = (lane >> 2);
    const int st_off = (lane & 3) * 16;

    f32x4 acc[4][NI] = {};

    const char* Ab = (const char*)(A + (size_t)row0 * K);
    const char* Bb = (const char*)(Wt + (size_t)col0 * K);
    const size_t strideA = (size_t)K * 2;

    for (int k0 = 0; k0 < K; k0 += 32) {
        if (MT == 128) {
#pragma unroll
            for (int issue = 0; issue < 2; ++issue) {
                const int r = wave * 32 + issue * 16 + st_row;
                gld_lds16((char*)As + (wave * 32 + issue * 16) * 64,
                          Ab + (size_t)r * strideA + k0 * 2 + st_off);
            }
        } else {
            const int r = wave * 16 + st_row;
            gld_lds16((char*)As + (wave * 16) * 64,
                      Ab + (size_t)r * strideA + k0 * 2 + st_off);
        }
#pragma unroll
        for (int issue = 0; issue < 2; ++issue) {
            const int r = wave * 32 + issue * 16 + st_row;
            gld_lds16((char*)Bs + (wave * 32 + issue * 16) * 64,
                      Bb + (size_t)r * strideA + k0 * 2 + st_off);
        }
        __syncthreads();
        bf16x8 af[4], bfr[NI];
#pragma unroll
        for (int mi = 0; mi < 4; ++mi)
            af[mi] = *(const bf16x8*)&As[(wr + mi * 16 + mrow) * 32 + kq];
#pragma unroll
        for (int ni = 0; ni < NI; ++ni)
            bfr[ni] = *(const bf16x8*)&Bs[(wc + ni * 16 + mrow) * 32 + kq];
#pragma unroll
        for (int mi = 0; mi < 4; ++mi)
#pragma unroll
            for (int ni = 0; ni < NI; ++ni)
                acc[mi][ni] = __builtin_amdgcn_mfma_f32_16x16x32_bf16(
                    af[mi], bfr[ni], acc[mi][ni], 0, 0, 0);
        __syncthreads();
    }

    const int quad = lane >> 4;
    float bv[NI];
#pragma unroll
    for (int ni = 0; ni < NI; ++ni) bv[ni] = bias[col0 + wc + ni * 16 + mrow];
#pragma unroll
    for (int mi = 0; mi < 4; ++mi) {
#pragma unroll
        for (int r = 0; r < 4; ++r) {
            const int row = row0 + wr + mi * 16 + quad * 4 + r;
#pragma unroll
            for (int ni = 0; ni < NI; ++ni) {
                const int col = col0 + wc + ni * 16 + mrow;
                float v = acc[mi][ni][r] + bv[ni];
                if (RES) v += R[(size_t)row * N + col];
                v *= sc;
                if (RELU) v = fmaxf(v, 0.0f);
                if (OUT_BF16) ((bf16*)C)[(size_t)row * N + col] = (bf16)v;
                else          ((float*)C)[(size_t)row * N + col] = v;
            }
        }
    }
}

// ---------------- Transposed-S MFMA flash attention, double-buffered ----------------
// S^T = K·Q^T (lane's C-column = fixed query q = lane&15); P^T re-layout via
// quad-level shfl (no LDS round trip). Q pre-scaled by 0.125*log2(e).
// grid: (32, H, B) = 768 blocks; block does q-tiles {63-bx, bx} -> uniform 65
// iters (load balance). K/V LDS double-buffered: next tile's global loads are
// issued BEFORE compute, LDS writes after -> staging latency overlaps compute;
// exactly 1 barrier per K-iteration.
__global__ __launch_bounds__(256) void mattn_kernel(
    const bf16* __restrict__ Q, const bf16* __restrict__ K,
    const bf16* __restrict__ V, const int* __restrict__ amask,
    bf16* __restrict__ O) {
    const int bx = blockIdx.x, h = blockIdx.y, b = blockIdx.z;

    __shared__ bf16 Ks[2][64][68];   // [buf][key][d]  (136 B rows: conflict-free)
    __shared__ bf16 Vt[2][64][68];   // [buf][d][key]
    __shared__ bf16 Os[64][68];      // epilogue bounce
    __shared__ float mk[2][64];
    __shared__ int flagv[2];

    const int tid = threadIdx.x;
    const int wave = tid >> 6, lane = tid & 63;
    const int l = lane & 15, quad = lane >> 4;
    const int qh = quad >> 1;
    const int srcA = (quad & 1) * 32 + l;
    const int srcB = srcA + 16;
    const float NEG_INF = -__builtin_huge_valf();

    const int kr = tid >> 2, ks = (tid & 3) * 16;          // K tile staging
    const int vk0 = (tid & 31) * 2, vds = (tid >> 5) * 8;  // V transpose staging

    const bf16* Kbase = K + (size_t)b * S_LEN * DMODEL + h * HDIM;
    const bf16* Vbase = V + (size_t)b * S_LEN * DMODEL + h * HDIM;

#pragma unroll 1
    for (int pass = 0; pass < 2; ++pass) {
        const int qt = pass ? bx : (63 - bx);

        // Q fragments (B-operand), pre-scaled, held in registers
        const bf16* Qb = Q + (size_t)(b * S_LEN + qt * 64 + wave * 16 + l) * DMODEL + h * HDIM;
        const bf16x8 qf0 = *(const bf16x8*)(Qb + quad * 8);
        const bf16x8 qf1 = *(const bf16x8*)(Qb + 32 + quad * 8);

        float m_run = NEG_INF, l_run = 0.0f;
        f32x4 acc[4] = {};

        // ---- prefetch tile 0 into registers ----
        bf16x8 kp0, kp1, vp0, vp1;
        int mv = 1;
        {
            const bf16* kg = Kbase + (size_t)kr * DMODEL + ks;
            kp0 = *(const bf16x8*)kg;
            kp1 = *(const bf16x8*)(kg + 8);
            const bf16* vg = Vbase + (size_t)vk0 * DMODEL + vds;
            vp0 = *(const bf16x8*)vg;
            vp1 = *(const bf16x8*)(vg + DMODEL);
            if (wave == 0) mv = amask[b * S_LEN + lane];
        }
        __syncthreads();   // prior pass epilogue LDS reads complete
        {   // write tile 0 to buf 0
            *(bf16x8*)&Ks[0][kr][ks]     = kp0;
            *(bf16x8*)&Ks[0][kr][ks + 8] = kp1;
#pragma unroll
            for (int i = 0; i < 8; ++i) {
                U2 w; w.h[0] = vp0[i]; w.h[1] = vp1[i];
                *(unsigned*)&Vt[0][vds + i][vk0] = w.u;
            }
            if (wave == 0) {
                mk[0][lane] = mv ? 0.0f : NEG_INF;
                unsigned long long bal = __ballot(mv != 0);
                if (lane == 0) flagv[0] = (bal == ~0ULL);
            }
        }
        __syncthreads();
        int buf = 0;

        for (int kt = 0; kt <= qt; ++kt) {
            const bool more = (kt < qt);
            // ---- issue next tile's global loads (consumed after compute) ----
            if (more) {
                const bf16* kg = Kbase + (size_t)((kt + 1) * 64 + kr) * DMODEL + ks;
                kp0 = *(const bf16x8*)kg;
                kp1 = *(const bf16x8*)(kg + 8);
                const bf16* vg = Vbase + (size_t)((kt + 1) * 64 + vk0) * DMODEL + vds;
                vp0 = *(const bf16x8*)vg;
                vp1 = *(const bf16x8*)(vg + DMODEL);
                if (wave == 0) mv = amask[b * S_LEN + (kt + 1) * 64 + lane];
            }

            // ---- compute on buf ----
            const int allv = flagv[buf];
            f32x4 sreg[4] = {};
#pragma unroll
            for (int mi = 0; mi < 4; ++mi) {
                bf16x8 kf0 = *(const bf16x8*)&Ks[buf][mi * 16 + l][quad * 8];
                bf16x8 kf1 = *(const bf16x8*)&Ks[buf][mi * 16 + l][32 + quad * 8];
                sreg[mi] = __builtin_amdgcn_mfma_f32_16x16x32_bf16(kf0, qf0, sreg[mi], 0, 0, 0);
                sreg[mi] = __builtin_amdgcn_mfma_f32_16x16x32_bf16(kf1, qf1, sreg[mi], 0, 0, 0);
            }
            if (!allv) {
#pragma unroll
                for (int mi = 0; mi < 4; ++mi) {
                    F4 m4; m4.v = *(const float4*)&mk[buf][mi * 16 + quad * 4];
#pragma unroll
                    for (int r = 0; r < 4; ++r) sreg[mi][r] += m4.f[r];
                }
            }
            if (kt == qt) {   // diagonal tile: causal mask
#pragma unroll
                for (int mi = 0; mi < 4; ++mi)
#pragma unroll
                    for (int r = 0; r < 4; ++r)
                        if (mi * 16 + quad * 4 + r > wave * 16 + l)
                            sreg[mi][r] = NEG_INF;
            }

            // online softmax (per-lane: one query's 16 keys; 2 shfl levels)
            float mloc = sreg[0][0];
#pragma unroll
            for (int mi = 0; mi < 4; ++mi)
#pragma unroll
                for (int r = 0; r < 4; ++r) mloc = fmaxf(mloc, sreg[mi][r]);
            mloc = fmaxf(mloc, __shfl_xor(mloc, 16, 64));
            mloc = fmaxf(mloc, __shfl_xor(mloc, 32, 64));
            const float mn = fmaxf(m_run, mloc);
            const float alpha = __builtin_amdgcn_exp2f(m_run - mn);
            m_run = mn;
            float ls = 0.0f;
#pragma unroll
            for (int mi = 0; mi < 4; ++mi)
#pragma unroll
                for (int r = 0; r < 4; ++r) {
                    const float p = __builtin_amdgcn_exp2f(sreg[mi][r] - mn);
                    sreg[mi][r] = p;
                    ls += p;
                }
            ls += __shfl_xor(ls, 16, 64);
            ls += __shfl_xor(ls, 32, 64);
            l_run = l_run * alpha + ls;
#pragma unroll
            for (int mi = 0; mi < 4; ++mi)
#pragma unroll
                for (int r = 0; r < 4; ++r) acc[mi][r] *= alpha;

            // pack P^T to bf16 dwords, assemble B-frags via quad-level shfl
            unsigned pk[4][2];
#pragma unroll
            for (int mi = 0; mi < 4; ++mi) {
                U2 w0; w0.h[0] = (bf16)sreg[mi][0]; w0.h[1] = (bf16)sreg[mi][1];
                U2 w1; w1.h[0] = (bf16)sreg[mi][2]; w1.h[1] = (bf16)sreg[mi][3];
                pk[mi][0] = w0.u; pk[mi][1] = w1.u;
            }
            bf16x8 pfrag[2];
#pragma unroll
            for (int kc = 0; kc < 2; ++kc) {
                U8 u;
#pragma unroll
                for (int t = 0; t < 2; ++t) {
                    const unsigned a0 = (unsigned)__shfl((int)pk[2 * kc][t],     srcA, 64);
                    const unsigned b0 = (unsigned)__shfl((int)pk[2 * kc + 1][t], srcA, 64);
                    u.u[t] = qh ? b0 : a0;
                    const unsigned a1 = (unsigned)__shfl((int)pk[2 * kc][t],     srcB, 64);
                    const unsigned b1 = (unsigned)__shfl((int)pk[2 * kc + 1][t], srcB, 64);
                    u.u[2 + t] = qh ? b1 : a1;
                }
                pfrag[kc] = u.v;
            }
            // O^T += V^T · P^T
#pragma unroll
            for (int mi = 0; mi < 4; ++mi) {
                bf16x8 vf0 = *(const bf16x8*)&Vt[buf][mi * 16 + l][quad * 8];
                bf16x8 vf1 = *(const bf16x8*)&Vt[buf][mi * 16 + l][32 + quad * 8];
                acc[mi] = __builtin_amdgcn_mfma_f32_16x16x32_bf16(vf0, pfrag[0], acc[mi], 0, 0, 0);
                acc[mi] = __builtin_amdgcn_mfma_f32_16x16x32_bf16(vf1, pfrag[1], acc[mi], 0, 0, 0);
            }

            // ---- write prefetched tile into the other buffer ----
            if (more) {
                const int nb = buf ^ 1;
                *(bf16x8*)&Ks[nb][kr][ks]     = kp0;
                *(bf16x8*)&Ks[nb][kr][ks + 8] = kp1;
#pragma unroll
                for (int i = 0; i < 8; ++i) {
                    U2 w; w.h[0] = vp0[i]; w.h[1] = vp1[i];
                    *(unsigned*)&Vt[nb][vds + i][vk0] = w.u;
                }
                if (wave == 0) {
                    mk[nb][lane] = mv ? 0.0f : NEG_INF;
                    unsigned long long bal = __ballot(mv != 0);
                    if (lane == 0) flagv[nb] = (bal == ~0ULL);
                }
            }
            __syncthreads();
            buf ^= 1;
        }

        // epilogue: lane owns query q = wave*16+l, d = mi*16+quad*4+r
        const float rinv = 1.0f / l_run;
#pragma unroll
        for (int mi = 0; mi < 4; ++mi) {
            U2 w0; w0.h[0] = (bf16)(acc[mi][0] * rinv); w0.h[1] = (bf16)(acc[mi][1] * rinv);
            U2 w1; w1.h[0] = (bf16)(acc[mi][2] * rinv); w1.h[1] = (bf16)(acc[mi][3] * rinv);
            *(unsigned*)&Os[wave * 16 + l][mi * 16 + quad * 4]     = w0.u;
            *(unsigned*)&Os[wave * 16 + l][mi * 16 + quad * 4 + 2] = w1.u;
        }
        __syncthreads();
        {   // coalesced store
            const int orow = tid >> 2, oseg = (tid & 3) * 16;
            bf16* Og = O + (size_t)(b * S_LEN + qt * 64 + orow) * DMODEL + h * HDIM + oseg;
            *(bf16x8*)Og       = *(const bf16x8*)&Os[orow][oseg];
            *(bf16x8*)(Og + 8) = *(const bf16x8*)&Os[orow][oseg + 8];
        }
    }
}

// ---------------- launcher ----------------
extern "C" void kernel_launch(void* const* d_in, const int* in_sizes, int n_in,
                              void* d_out, int out_size, void* d_ws, size_t ws_size,
                              hipStream_t stream) {
    const float* x     = (const float*)d_in[0];
    const int*   amask = (const int*)  d_in[1];
    const float* ln1_g = (const float*)d_in[2];
    const float* ln1_b = (const float*)d_in[3];
    const float* ln2_g = (const float*)d_in[4];
    const float* ln2_b = (const float*)d_in[5];
    const float* Wq = (const float*)d_in[6];  const float* bq = (const float*)d_in[7];
    const float* Wk = (const float*)d_in[8];  const float* bk = (const float*)d_in[9];
    const float* Wv = (const float*)d_in[10]; const float* bv = (const float*)d_in[11];
    const float* Wo = (const float*)d_in[12]; const float* bo = (const float*)d_in[13];
    const float* W1 = (const float*)d_in[14]; const float* b1 = (const float*)d_in[15];
    const float* W2 = (const float*)d_in[16]; const float* b2 = (const float*)d_in[17];
    float* out = (float*)d_out;

    char* ws = (char*)d_ws;
    const size_t WSML = (size_t)DMODEL * DMODEL * 2;
    const size_t WBIG = (size_t)DMODEL * DFF_ * 2;
    bf16* Wqt = (bf16*)(ws + 0 * WSML);
    bf16* Wkt = (bf16*)(ws + 1 * WSML);
    bf16* Wvt = (bf16*)(ws + 2 * WSML);
    bf16* Wot = (bf16*)(ws + 3 * WSML);
    bf16* W1t = (bf16*)(ws + 4 * WSML);
    bf16* W2t = (bf16*)(ws + 4 * WSML + WBIG);
    char* act = ws + 4 * WSML + 2 * WBIG;

    const size_t HB = (size_t)MROWS * DMODEL * 2;   // bf16 activation
    const size_t FB = (size_t)MROWS * DMODEL * 4;   // fp32 activation
    bf16*  h    = (bf16*)(act);            // LN1 out; later ctx; later h2
    bf16*  qb   = (bf16*)(act + HB);
    bf16*  kb   = (bf16*)(act + 2 * HB);
    bf16*  vb   = (bf16*)(act + 3 * HB);
    bf16*  ctx  = h;
    float* x1   = (float*)(act + 4 * HB);
    bf16*  f    = (bf16*)(act + 4 * HB + FB);
    bf16*  h2   = h;

    const float SCL = 0.125f * 1.44269504089f;  // 1/sqrt(64) * log2(e), folded into Q

    // 0. weight transpose+convert
    wtrans_kernel<<<dim3(DMODEL / 64, DMODEL / 64), 256, 0, stream>>>(Wq, Wqt, DMODEL, DMODEL);
    wtrans_kernel<<<dim3(DMODEL / 64, DMODEL / 64), 256, 0, stream>>>(Wk, Wkt, DMODEL, DMODEL);
    wtrans_kernel<<<dim3(DMODEL / 64, DMODEL / 64), 256, 0, stream>>>(Wv, Wvt, DMODEL, DMODEL);
    wtrans_kernel<<<dim3(DMODEL / 64, DMODEL / 64), 256, 0, stream>>>(Wo, Wot, DMODEL, DMODEL);
    wtrans_kernel<<<dim3(DFF_ / 64, DMODEL / 64), 256, 0, stream>>>(W1, W1t, DMODEL, DFF_);
    wtrans_kernel<<<dim3(DMODEL / 64, DFF_ / 64), 256, 0, stream>>>(W2, W2t, DFF_, DMODEL);

    // 1. LN1 -> h (bf16)
    ln_kernel<bf16><<<MROWS, 256, 0, stream>>>(x, ln1_g, ln1_b, h);
    // 2. QKV fused, bf16 out; Q pre-scaled by SCL  (1152 blocks)
    mgemm_kernel<128, false, false, true><<<dim3(DMODEL / 128, MROWS / 128, 3), 256, 0, stream>>>(
        h, Wqt, bq, qb, Wkt, bk, kb, Wvt, bv, vb, nullptr, MROWS, DMODEL, DMODEL,
        SCL, 1.0f, 1.0f);
    // 3. transposed-S MFMA flash attention -> ctx (bf16)  (768 balanced blocks)
    mattn_kernel<<<dim3(32, NHEAD, 2), 256, 0, stream>>>(qb, kb, vb, amask, ctx);
    // 4. out proj + residual(x) -> x1 (fp32)  (MT=64: 768 blocks)
    mgemm_kernel<64, false, true, false><<<dim3(DMODEL / 128, MROWS / 64, 1), 256, 0, stream>>>(
        ctx, Wot, bo, x1, Wot, bo, x1, Wot, bo, x1, x, MROWS, DMODEL, DMODEL,
        1.0f, 1.0f, 1.0f);
    // 5. LN2 -> h2 (bf16)
    ln_kernel<bf16><<<MROWS, 256, 0, stream>>>(x1, ln2_g, ln2_b, h2);
    // 6. FF1 + relu -> f (bf16)  (1536 blocks)
    mgemm_kernel<128, true, false, true><<<dim3(DFF_ / 128, MROWS / 128, 1), 256, 0, stream>>>(
        h2, W1t, b1, f, W1t, b1, f, W1t, b1, f, nullptr, MROWS, DFF_, DMODEL,
        1.0f, 1.0f, 1.0f);
    // 7. FF2 + residual(x1) -> out (fp32)  (MT=64: 768 blocks)
    mgemm_kernel<64, false, true, false><<<dim3(DMODEL / 128, MROWS / 64, 1), 256, 0, stream>>>(
        f, W2t, b2, out, W2t, b2, out, W2t, b2, out, x1, MROWS, DMODEL, DFF_,
        1.0f, 1.0f, 1.0f);
}